// Round 2
// baseline (7524.085 us; speedup 1.0000x reference)
//
#include <hip/hip_runtime.h>
#include <math.h>

#define HID 512
#define TENC 16384
#define NBLK 256
#define TPB 1024
#define VOCAB 31
#define EOSI 29
#define MAXLEN 100
#define SCALE 0.044194173824159216f

// ws layout (float units)
#define WS_GX    0          // 31*1536
#define WS_GH    47616      // 1536
#define WS_H     49152      // 2*512 (double buffer)
#define WS_SUMRY 50176      // 512
#define WS_M     50688      // 256
#define WS_S     50944      // 256
#define WS_U     51200      // 256*512
#define WS_BAR   182272     // 300 ints

// d_out layout: [0..3099] logits, [3100] length (float), [3101..] attn (100*16384)
#define OUT_LEN_IDX 3100
#define OUT_ATT_BASE 3101

static __device__ __forceinline__ float wsum(float v) {
#pragma unroll
  for (int m = 32; m >= 1; m >>= 1) v += __shfl_xor(v, m, 64);
  return v;
}
static __device__ __forceinline__ float sigm(float x) { return 1.0f / (1.0f + expf(-x)); }

__global__ __launch_bounds__(512) void k_init(float* ws) {
  int tid = threadIdx.x;
  if (tid < HID) ws[WS_H + tid] = 0.0f;         // h[0] = 0
  int* bars = (int*)ws + WS_BAR;
  if (tid < 3 * MAXLEN) bars[tid] = 0;
}

// GX_all[v][r] = w_ih[r,:]·embed[v,:] + b_ih[r]
__global__ __launch_bounds__(256) void k_gx_all(const float* __restrict__ embed,
                                                const float* __restrict__ w_ih,
                                                const float* __restrict__ b_ih,
                                                float* __restrict__ ws) {
  int w = threadIdx.x >> 6, lane = threadIdx.x & 63;
  int r = blockIdx.x * 4 + w;
  float wr[8];
  const float* wp = w_ih + (size_t)r * HID + lane * 8;
#pragma unroll
  for (int j = 0; j < 8; ++j) wr[j] = wp[j];
  float b = b_ih[r];
  for (int v = 0; v < VOCAB; ++v) {
    const float* e = embed + (size_t)v * HID + lane * 8;
    float d = 0.f;
#pragma unroll
    for (int j = 0; j < 8; ++j) d += wr[j] * e[j];
    d = wsum(d);
    if (lane == 0) ws[WS_GX + v * 1536 + r] = d + b;
  }
}

static __device__ __forceinline__ void gridbar(int* bar) {
  __syncthreads();
  if (threadIdx.x == 0) {
    __threadfence();
    __hip_atomic_fetch_add(bar, 1, __ATOMIC_RELEASE, __HIP_MEMORY_SCOPE_AGENT);
    while (__hip_atomic_load(bar, __ATOMIC_RELAXED, __HIP_MEMORY_SCOPE_AGENT) < NBLK)
      __builtin_amdgcn_s_sleep(1);
    __threadfence();
  }
  __syncthreads();
}

__global__ __launch_bounds__(TPB, 4) void k_persist(const float* __restrict__ enc,
                                                    const float* __restrict__ w_hh,
                                                    const float* __restrict__ b_hh,
                                                    const float* __restrict__ w_out,
                                                    const float* __restrict__ b_out,
                                                    float* __restrict__ ws,
                                                    float* __restrict__ dout) {
  const int tid = threadIdx.x, blk = blockIdx.x;
  const int w = tid >> 6, lane = tid & 63;
  __shared__ float hn[HID];
  __shared__ float sblk[64];
  __shared__ float uld[HID];
  __shared__ float red[32];
  __shared__ float lgs[32];
  __shared__ float bMS[1];
  int best = EOSI;
  int len = MAXLEN;
  int* bars = (int*)ws + WS_BAR;

#pragma unroll 1
  for (int t = 0; t <= MAXLEN; ++t) {
    const float* h = ws + WS_H + (t & 1) * HID;
    // ---------------- phase A: logits[t-1] + argmax + gh ----------------
    if (t > 0) {
      for (int r = w; r < VOCAB; r += 16) {
        const float* wo = w_out + (size_t)r * 1024;
        float acc = 0.f;
#pragma unroll
        for (int k = 0; k < 2; ++k) {
          int d = k * 256 + lane * 4;
          float4 wv = *(const float4*)(wo + d);
          float4 xv = *(const float4*)(ws + WS_SUMRY + d);
          acc += wv.x * xv.x + wv.y * xv.y + wv.z * xv.z + wv.w * xv.w;
        }
#pragma unroll
        for (int k = 0; k < 2; ++k) {
          int d = k * 256 + lane * 4;
          float4 wv = *(const float4*)(wo + 512 + d);
          float4 xv = *(const float4*)(h + d);
          acc += wv.x * xv.x + wv.y * xv.y + wv.z * xv.z + wv.w * xv.w;
        }
        acc = wsum(acc);
        if (lane == 0) lgs[r] = acc + b_out[r];
      }
      __syncthreads();
      float bv = lgs[0];
      int bb = 0;
#pragma unroll
      for (int v = 1; v < VOCAB; ++v) {
        float x = lgs[v];
        if (x > bv) { bv = x; bb = v; }
      }
      best = bb;
      if (bb == EOSI && len == MAXLEN) len = t - 1;
      if (blk == 0) {
        if (tid < VOCAB) dout[(size_t)(t - 1) * VOCAB + tid] = lgs[tid];
        if (t == MAXLEN && tid == 0) dout[OUT_LEN_IDX] = (float)len;
      }
    }
    if (t == MAXLEN) break;
    // gh slice: rows blk*6 .. blk*6+5
    {
      int r0 = blk * 6;
      for (int r = r0 + w; r < r0 + 6; r += 16) {
        const float* wp = w_hh + (size_t)r * HID;
        float acc = 0.f;
#pragma unroll
        for (int k = 0; k < 2; ++k) {
          int d = k * 256 + lane * 4;
          float4 wv = *(const float4*)(wp + d);
          float4 hv = *(const float4*)(h + d);
          acc += wv.x * hv.x + wv.y * hv.y + wv.z * hv.z + wv.w * hv.w;
        }
        acc = wsum(acc);
        if (lane == 0) ws[WS_GH + r] = acc + b_hh[r];
      }
    }
    gridbar(&bars[t * 3 + 0]);

    // ---------------- phase B: h_new, scores, PV partials ----------------
    const float* gx = ws + WS_GX + best * 1536;
    const float* gh = ws + WS_GH;
    if (tid < HID) {
      float rg = sigm(gx[tid] + gh[tid]);
      float zg = sigm(gx[HID + tid] + gh[HID + tid]);
      float ng = tanhf(gx[2 * HID + tid] + rg * gh[2 * HID + tid]);
      hn[tid] = (1.f - zg) * ng + zg * h[tid];
    }
    if (tid < HID) uld[tid] = 0.f;
    __syncthreads();
    if (blk == 0 && tid < HID) ws[WS_H + ((t + 1) & 1) * HID + tid] = hn[tid];
    float hr[8];
#pragma unroll
    for (int j = 0; j < 8; ++j) hr[j] = hn[lane * 8 + j];
    float4 vv[4][2];
#pragma unroll
    for (int rr = 0; rr < 4; ++rr) {
      int trow = blk * 64 + w * 4 + rr;
      const float4* kp = (const float4*)(enc + (size_t)trow * 1024 + lane * 8);
      float4 k0 = kp[0], k1 = kp[1];
      float d = hr[0] * k0.x + hr[1] * k0.y + hr[2] * k0.z + hr[3] * k0.w
              + hr[4] * k1.x + hr[5] * k1.y + hr[6] * k1.z + hr[7] * k1.w;
      bool okl = (k0.x != 30.f) || (k0.y != 30.f) || (k0.z != 30.f) || (k0.w != 30.f)
               || (k1.x != 30.f) || (k1.y != 30.f) || (k1.z != 30.f) || (k1.w != 30.f);
      float s = wsum(d);
      bool ok = (__ballot(okl) != 0ull);
      s = ok ? s * SCALE : -1000000000.0f;
      if (lane == 0) sblk[w * 4 + rr] = s;
      const float4* vp = (const float4*)(enc + (size_t)trow * 1024 + 512 + lane * 8);
      vv[rr][0] = vp[0];
      vv[rr][1] = vp[1];
    }
    __syncthreads();
    if (tid < 64) {
      float m = sblk[tid];
#pragma unroll
      for (int msk = 32; msk >= 1; msk >>= 1) m = fmaxf(m, __shfl_xor(m, msk, 64));
      if (tid == 0) bMS[0] = m;
    }
    __syncthreads();
    float m_b = bMS[0];
    {
      float ps[8] = {0, 0, 0, 0, 0, 0, 0, 0};
#pragma unroll
      for (int rr = 0; rr < 4; ++rr) {
        float a = expf(sblk[w * 4 + rr] - m_b);
        float4 v0 = vv[rr][0], v1 = vv[rr][1];
        ps[0] += a * v0.x; ps[1] += a * v0.y; ps[2] += a * v0.z; ps[3] += a * v0.w;
        ps[4] += a * v1.x; ps[5] += a * v1.y; ps[6] += a * v1.z; ps[7] += a * v1.w;
      }
#pragma unroll
      for (int j = 0; j < 8; ++j) atomicAdd(&uld[lane * 8 + j], ps[j]);
    }
    if (tid < 64) {
      float e = expf(sblk[tid] - m_b);
      e = wsum(e);
      if (tid == 0) { ws[WS_M + blk] = m_b; ws[WS_S + blk] = e; }
    }
    __syncthreads();
    if (tid < HID) ws[WS_U + (size_t)blk * HID + tid] = uld[tid];
    gridbar(&bars[t * 3 + 1]);

    // ---------------- phase C: global M,S; attn; summary dims ----------------
    if (w < 4) {
      float m = ws[WS_M + tid], s = ws[WS_S + tid];
#pragma unroll
      for (int msk = 32; msk >= 1; msk >>= 1) {
        float m2 = __shfl_xor(m, msk, 64), s2 = __shfl_xor(s, msk, 64);
        float Mn = fmaxf(m, m2);
        s = s * expf(m - Mn) + s2 * expf(m2 - Mn);
        m = Mn;
      }
      if (lane == 0) { red[w * 2] = m; red[w * 2 + 1] = s; }
    }
    __syncthreads();
    float M = red[0], S = red[1];
#pragma unroll
    for (int k = 1; k < 4; ++k) {
      float m2 = red[k * 2], s2 = red[k * 2 + 1];
      float Mn = fmaxf(M, m2);
      S = S * expf(M - Mn) + s2 * expf(m2 - Mn);
      M = Mn;
    }
    float invS = 1.0f / S;
    if (tid < 64) {
      float a = expf(sblk[tid] - M) * invS;
      dout[OUT_ATT_BASE + (size_t)t * TENC + blk * 64 + tid] = a;
    }
    if (w < 4) {
      int d0 = blk * 2;
      float e = expf(ws[WS_M + tid] - M);
      float a0 = e * ws[WS_U + (size_t)tid * HID + d0];
      float a1 = e * ws[WS_U + (size_t)tid * HID + d0 + 1];
      a0 = wsum(a0);
      a1 = wsum(a1);
      if (lane == 0) { red[8 + w * 2] = a0; red[8 + w * 2 + 1] = a1; }
    }
    __syncthreads();
    if (tid == 0) {
      int d0 = blk * 2;
      float s0 = red[8] + red[10] + red[12] + red[14];
      float s1 = red[9] + red[11] + red[13] + red[15];
      ws[WS_SUMRY + d0] = s0 * invS;
      ws[WS_SUMRY + d0 + 1] = s1 * invS;
    }
    gridbar(&bars[t * 3 + 2]);
  }
}

extern "C" void kernel_launch(void* const* d_in, const int* in_sizes, int n_in,
                              void* d_out, int out_size, void* d_ws, size_t ws_size,
                              hipStream_t stream) {
  const float* enc   = (const float*)d_in[0];
  const float* embed = (const float*)d_in[2];
  const float* w_ih  = (const float*)d_in[3];
  const float* w_hh  = (const float*)d_in[4];
  const float* b_ih  = (const float*)d_in[5];
  const float* b_hh  = (const float*)d_in[6];
  const float* w_out = (const float*)d_in[7];
  const float* b_out = (const float*)d_in[8];
  float* dout = (float*)d_out;
  float* ws = (float*)d_ws;

  hipLaunchKernelGGL(k_init, dim3(1), dim3(512), 0, stream, ws);
  hipLaunchKernelGGL(k_gx_all, dim3(384), dim3(256), 0, stream, embed, w_ih, b_ih, ws);
  hipLaunchKernelGGL(k_persist, dim3(NBLK), dim3(TPB), 0, stream,
                     enc, w_hh, b_hh, w_out, b_out, ws, dout);
}